// Round 5
// baseline (434.369 us; speedup 1.0000x reference)
//
#include <hip/hip_runtime.h>
#include <math.h>

#define NN 20000
#define EE 320000
#define DD 256
#define ETOT (EE + NN)
#define EDGE_CAP 1544   // max edges per 32-dst group (mean 544) + 4 align slack + 4 overshoot
#define NCHUNK ((NN + 255) / 256)  // 79 scan chunks

typedef __attribute__((ext_vector_type(8))) short bf8;
typedef __attribute__((ext_vector_type(4))) float f32x4;

__device__ __forceinline__ float gelu_exact(float x) {
    return 0.5f * x * (1.0f + erff(x * 0.70710678118654752f));
}

// round-to-nearest-even f32 -> bf16 bits
__device__ __forceinline__ unsigned short f2bf(float v) {
    unsigned u = __float_as_uint(v);
    u += 0x7fffu + ((u >> 16) & 1u);
    return (unsigned short)(u >> 16);
}
__device__ __forceinline__ float bf2f(unsigned short h) {
    return __uint_as_float(((unsigned)h) << 16);
}
__device__ __forceinline__ void split2(float v, unsigned short& hi, unsigned short& lo) {
    hi = f2bf(v);
    lo = f2bf(v - bf2f(hi));
}

// ---------------- row-normalize + split X; zero s/d buffers; init deg ----------------
__global__ __launch_bounds__(256) void norm_k(const float* __restrict__ X,
                                              unsigned short* __restrict__ Xh,
                                              unsigned short* __restrict__ Xl,
                                              float* __restrict__ sdZero,  // 6*NN floats
                                              int* __restrict__ deg) {
    int t = threadIdx.x;
    int bid = blockIdx.x;  // 0..4999
    // side duties: zero 24 floats of s/d buffers, init 4 deg entries to 1 (self loop)
    if (t < 24) sdZero[bid * 24 + t] = 0.0f;
    if (t >= 32 && t < 36) deg[bid * 4 + (t - 32)] = 1;

    int wave = (bid * 256 + t) >> 6;
    int lane = t & 63;
    const float4 v = *(const float4*)&X[wave * DD + lane * 4];
    float ss = v.x * v.x + v.y * v.y + v.z * v.z + v.w * v.w;
    for (int off = 32; off > 0; off >>= 1) ss += __shfl_down(ss, off, 64);
    ss = __shfl(ss, 0, 64);
    float n = sqrtf(ss);
    if (n == 0.0f) n = 1e-8f;
    float inv = 1.0f / n;
    float o[4] = {v.x * inv, v.y * inv, v.z * inv, v.w * inv};
    ushort4 hv, lv;
    split2(o[0], hv.x, lv.x);
    split2(o[1], hv.y, lv.y);
    split2(o[2], hv.z, lv.z);
    split2(o[3], hv.w, lv.w);
    *(ushort4*)&Xh[wave * DD + lane * 4] = hv;
    *(ushort4*)&Xl[wave * DD + lane * 4] = lv;
}

// ---------------- W transpose + hi/lo split for all 3 layers (z = layer) ----------------
__global__ __launch_bounds__(256) void splitw_k(const float* __restrict__ W1, const float* __restrict__ W2,
                                                const float* __restrict__ W3, unsigned short* __restrict__ Whl) {
    __shared__ float tile[64][65];
    int t = threadIdx.x;
    int k0 = blockIdx.x * 64;
    int c0 = blockIdx.y * 64;
    int z = blockIdx.z;
    const float* W = (z == 0) ? W1 : (z == 1) ? W2 : W3;
    unsigned short* Wht = Whl + (size_t)z * 2 * DD * DD;
    unsigned short* Wlt = Wht + DD * DD;
#pragma unroll
    for (int i = 0; i < 16; ++i) {
        int idx = t + i * 256;
        int r = idx >> 6, c = idx & 63;
        tile[r][c] = W[(k0 + r) * DD + c0 + c];
    }
    __syncthreads();
#pragma unroll
    for (int i = 0; i < 16; ++i) {
        int idx = t + i * 256;
        int r = idx >> 6, c = idx & 63;
        float v = tile[c][r];
        unsigned short hi, lo;
        split2(v, hi, lo);
        Wht[(c0 + r) * DD + k0 + c] = hi;
        Wlt[(c0 + r) * DD + k0 + c] = lo;
    }
}

// ---------------- CSR build ----------------
__global__ void count_k(const int* __restrict__ ei, int* deg) {
    int e = blockIdx.x * 256 + threadIdx.x;
    if (e < EE) atomicAdd(&deg[ei[EE + e]], 1);
}

// 3-pass parallel scan of deg[NN].
__global__ __launch_bounds__(256) void scanA_k(const int* __restrict__ deg, int* __restrict__ part) {
    __shared__ int red[256];
    int t = threadIdx.x;
    int idx = blockIdx.x * 256 + t;
    red[t] = (idx < NN) ? deg[idx] : 0;
    __syncthreads();
    for (int s = 128; s > 0; s >>= 1) {
        if (t < s) red[t] += red[t + s];
        __syncthreads();
    }
    if (t == 0) part[blockIdx.x] = red[0];
}

__global__ __launch_bounds__(128) void scanB_k(int* __restrict__ part, int* __restrict__ offs) {
    __shared__ int sh[NCHUNK];
    int t = threadIdx.x;
    if (t < NCHUNK) sh[t] = part[t];
    __syncthreads();
    if (t == 0) {
        int run = 0;
        for (int i = 0; i < NCHUNK; ++i) {
            int v = sh[i];
            sh[i] = run;
            run += v;
        }
        offs[NN] = run;  // == ETOT
    }
    __syncthreads();
    if (t < NCHUNK) part[t] = sh[t];
}

__global__ __launch_bounds__(256) void scanC_k(const int* __restrict__ deg, const int* __restrict__ part,
                                               int* __restrict__ offs, int* __restrict__ cursor,
                                               int* __restrict__ csr, int* __restrict__ csrD) {
    __shared__ int sh[256];
    int t = threadIdx.x;
    int idx = blockIdx.x * 256 + t;
    int v = (idx < NN) ? deg[idx] : 0;
    sh[t] = v;
    __syncthreads();
    for (int s = 1; s < 256; s <<= 1) {
        int u = (t >= s) ? sh[t - s] : 0;
        __syncthreads();
        sh[t] += u;
        __syncthreads();
    }
    if (idx < NN) {
        int run = part[blockIdx.x] + sh[t] - v;  // exclusive prefix
        offs[idx] = run;
        cursor[idx] = run + 1;  // slot 0 of segment = self loop
        csr[run] = idx;
        csrD[run] = idx;
    }
}

__global__ void fill_k(const int* __restrict__ ei, int* cursor, int* __restrict__ csr,
                       int* __restrict__ csrD) {
    int e = blockIdx.x * 256 + threadIdx.x;
    if (e < EE) {
        int s = ei[e];
        int d = ei[EE + e];
        int p = atomicAdd(&cursor[d], 1);
        csr[p] = s;
        csrD[p] = d;
    }
}

// ---------------- edge-parallel attention weights ----------------
__global__ __launch_bounds__(256) void alpha_k(const float* __restrict__ sArr,
                                               const float* __restrict__ dArr,
                                               const int* __restrict__ csr,
                                               const int* __restrict__ csrD,
                                               float* __restrict__ wArr) {
    int p = blockIdx.x * 256 + threadIdx.x;
    if (p < ETOT) {
        float a = sArr[csr[p]] + dArr[csrD[p]];
        a = (a > 0.0f) ? a : 0.2f * a;
        wArr[p] = expf(a);
    }
}

// ---------------- MFMA GEMM + fused s,d epilogue ----------------
// 64x128 tile, 4 waves (R2 config — R3's 32x128 regressed: per-block overhead doubled).
// LDB 36: 18-dword row stride -> 16 distinct bank starts for the 16 rows of each
// ds_read_b128 (LDB 40 gave period-8 starts -> ~8-way, 1.92M conflict cycles).
// Epilogue: H stored via per-wave LDS transpose (reusing the dead B-tile LDS) as
// float4 rows — 8 coalesced stores/lane instead of 32 scattered dword stores.
#define LDB 36
#define GX ((NN + 63) / 64)  // 313 gemm tile rows
__global__ __launch_bounds__(256) void gemm_sd(const unsigned short* __restrict__ Xh,
                                               const unsigned short* __restrict__ Xl,
                                               const unsigned short* __restrict__ Bh,
                                               const unsigned short* __restrict__ Bl,
                                               const float* __restrict__ a_s,
                                               const float* __restrict__ a_d,
                                               float* __restrict__ H,
                                               float* __restrict__ sArr,
                                               float* __restrict__ dArr) {
    __shared__ unsigned short sB[2 * 128 * LDB];
    unsigned short* sBh = sB;
    unsigned short* sBl = sB + 128 * LDB;
    int t = threadIdx.x;
    int m0 = blockIdx.x * 64;
    int n0 = blockIdx.y * 128;
    int w = t >> 6, l = t & 63;
    int rofs = l & 15, kch = l >> 4;

    f32x4 acc[8] = {};

    int c1 = t, c2 = t + 256;
    int br1 = c1 >> 2, bo1 = (c1 & 3) * 8;
    int br2 = c2 >> 2, bo2 = (c2 & 3) * 8;
    const unsigned short* Bh1 = &Bh[(n0 + br1) * DD + bo1];
    const unsigned short* Bh2 = &Bh[(n0 + br2) * DD + bo2];
    const unsigned short* Bl1 = &Bl[(n0 + br1) * DD + bo1];
    const unsigned short* Bl2 = &Bl[(n0 + br2) * DD + bo2];
    bf8 rbh1 = *(const bf8*)Bh1;
    bf8 rbh2 = *(const bf8*)Bh2;
    bf8 rbl1 = *(const bf8*)Bl1;
    bf8 rbl2 = *(const bf8*)Bl2;

    int arow = m0 + w * 16 + rofs;
    bool aval = arow < NN;
    const unsigned short* Ahp = &Xh[(size_t)arow * DD + kch * 8];
    const unsigned short* Alp = &Xl[(size_t)arow * DD + kch * 8];
    bf8 zero = {0, 0, 0, 0, 0, 0, 0, 0};
    bf8 ah = aval ? *(const bf8*)Ahp : zero;
    bf8 al = aval ? *(const bf8*)Alp : zero;

    for (int k0 = 0; k0 < DD; k0 += 32) {
        if (k0) __syncthreads();
        *(bf8*)&sBh[br1 * LDB + bo1] = rbh1;
        *(bf8*)&sBh[br2 * LDB + bo2] = rbh2;
        *(bf8*)&sBl[br1 * LDB + bo1] = rbl1;
        *(bf8*)&sBl[br2 * LDB + bo2] = rbl2;
        __syncthreads();
        int kn = k0 + 32;
        bf8 nah = zero, nal = zero;
        if (kn < DD) {
            rbh1 = *(const bf8*)(Bh1 + kn);
            rbh2 = *(const bf8*)(Bh2 + kn);
            rbl1 = *(const bf8*)(Bl1 + kn);
            rbl2 = *(const bf8*)(Bl2 + kn);
            if (aval) {
                nah = *(const bf8*)(Ahp + kn);
                nal = *(const bf8*)(Alp + kn);
            }
        }
#pragma unroll
        for (int nt = 0; nt < 8; ++nt) {
            int r = nt * 16 + rofs;
            bf8 bh = *(const bf8*)&sBh[r * LDB + kch * 8];
            bf8 bl = *(const bf8*)&sBl[r * LDB + kch * 8];
            acc[nt] = __builtin_amdgcn_mfma_f32_16x16x32_bf16(ah, bh, acc[nt], 0, 0, 0);
            acc[nt] = __builtin_amdgcn_mfma_f32_16x16x32_bf16(ah, bl, acc[nt], 0, 0, 0);
            acc[nt] = __builtin_amdgcn_mfma_f32_16x16x32_bf16(al, bh, acc[nt], 0, 0, 0);
        }
        ah = nah;
        al = nal;
    }
    // C/D layout: col = lane&15, row = (lane>>4)*4 + reg  [m89]
    int row0 = m0 + w * 16 + (l >> 4) * 4;
    int colb = l & 15;
    float sp[4] = {0, 0, 0, 0}, dp[4] = {0, 0, 0, 0};
#pragma unroll
    for (int nt = 0; nt < 8; ++nt) {
        int cc = n0 + nt * 16 + colb;
        float vas = a_s[cc], vad = a_d[cc];
#pragma unroll
        for (int r = 0; r < 4; ++r) {
            sp[r] += acc[nt][r] * vas;
            dp[r] += acc[nt][r] * vad;
        }
    }
#pragma unroll
    for (int m = 1; m < 16; m <<= 1) {
#pragma unroll
        for (int r = 0; r < 4; ++r) {
            sp[r] += __shfl_xor(sp[r], m, 64);
            dp[r] += __shfl_xor(dp[r], m, 64);
        }
    }
    if (colb == 0) {
#pragma unroll
        for (int r = 0; r < 4; ++r) {
            int row = row0 + r;
            if (row < NN) {
                atomicAdd(&sArr[row], sp[r]);
                atomicAdd(&dArr[row], dp[r]);
            }
        }
    }

    // ---- H store via per-wave LDS transpose (B-tile LDS is dead now) ----
    __syncthreads();  // all waves done reading sB
    float* wf = (float*)sB + w * (16 * 66);  // per-wave [16][66] f32
    int rrow = l >> 2;   // 0..15
    int cseg = l & 3;    // 0..3
    int grow = m0 + w * 16 + rrow;
#pragma unroll
    for (int c = 0; c < 2; ++c) {
#pragma unroll
        for (int nt4 = 0; nt4 < 4; ++nt4) {
#pragma unroll
            for (int r = 0; r < 4; ++r)
                wf[((l >> 4) * 4 + r) * 66 + nt4 * 16 + colb] = acc[c * 4 + nt4][r];
        }
        if (grow < NN) {
            float* Hrow = &H[(size_t)grow * DD + n0 + c * 64];
#pragma unroll
            for (int j = 0; j < 4; ++j)
                *(float4*)&Hrow[cseg * 4 + j * 16] = *(float4*)&wf[rrow * 66 + cseg * 4 + j * 16];
        }
    }
}

// ---------------- fused strip SpMM + bias + gelu + split ----------------
__global__ __launch_bounds__(256) void spmm_k(const float* __restrict__ H,
                                              const int* __restrict__ offs,
                                              const int* __restrict__ csr,
                                              const float* __restrict__ wArr,
                                              const float* __restrict__ bias,
                                              unsigned short* __restrict__ Oh,
                                              unsigned short* __restrict__ Ol,
                                              float* __restrict__ outf32) {
    __shared__ float wLds[EDGE_CAP];
    __shared__ int sLds[EDGE_CAP];
    int t = threadIdx.x;
    int sub = t & 7;
    int g = t >> 3;
    int dim = blockIdx.x * 32 + sub * 4;
    const float* Hs = H + dim;
    const float4 bvec = *(const float4*)&bias[dim];

    for (int grp = blockIdx.y; grp < NN / 32; grp += (int)gridDim.y) {
        if (grp != (int)blockIdx.y) __syncthreads();  // LDS reuse fence
        int dst0 = grp * 32;
        int dst = dst0 + g;
        int blkBeg = offs[dst0];
        int blkEnd = offs[dst0 + 32];
        int base = blkBeg & ~3;
        int cnt = blkEnd - base;
        // coalesced copy of this group's weight/src window into LDS
        for (int i = t * 4; i < cnt; i += 1024) {
            *(float4*)&wLds[i] = *(const float4*)&wArr[base + i];
            *(int4*)&sLds[i] = *(const int4*)&csr[base + i];
        }
        int beg = offs[dst], end = offs[dst + 1];
        __syncthreads();

        // den reduce (LDS only)
        float den = 0.0f;
        for (int e = beg + sub; e < end; e += 8) den += wLds[e - base];
        den += __shfl_xor(den, 1, 64);
        den += __shfl_xor(den, 2, 64);
        den += __shfl_xor(den, 4, 64);
        float inv = 1.0f / den;

        // gather pass: unnormalized accumulate
        float4 A0 = make_float4(0, 0, 0, 0), A1 = A0, A2 = A0, A3 = A0;
        int e = beg - base, lend = end - base;
        for (; e + 3 < lend; e += 4) {
            int s0 = sLds[e], s1 = sLds[e + 1], s2 = sLds[e + 2], s3 = sLds[e + 3];
            float w0 = wLds[e], w1 = wLds[e + 1], w2 = wLds[e + 2], w3 = wLds[e + 3];
            const float4 h0 = *(const float4*)&Hs[(size_t)s0 * DD];
            const float4 h1 = *(const float4*)&Hs[(size_t)s1 * DD];
            const float4 h2 = *(const float4*)&Hs[(size_t)s2 * DD];
            const float4 h3 = *(const float4*)&Hs[(size_t)s3 * DD];
            A0.x += w0 * h0.x; A0.y += w0 * h0.y; A0.z += w0 * h0.z; A0.w += w0 * h0.w;
            A1.x += w1 * h1.x; A1.y += w1 * h1.y; A1.z += w1 * h1.z; A1.w += w1 * h1.w;
            A2.x += w2 * h2.x; A2.y += w2 * h2.y; A2.z += w2 * h2.z; A2.w += w2 * h2.w;
            A3.x += w3 * h3.x; A3.y += w3 * h3.y; A3.z += w3 * h3.z; A3.w += w3 * h3.w;
        }
        for (; e < lend; ++e) {
            int s0 = sLds[e];
            float w0 = wLds[e];
            const float4 h0 = *(const float4*)&Hs[(size_t)s0 * DD];
            A0.x += w0 * h0.x; A0.y += w0 * h0.y; A0.z += w0 * h0.z; A0.w += w0 * h0.w;
        }

        float o0 = gelu_exact((A0.x + A1.x + A2.x + A3.x) * inv + bvec.x);
        float o1 = gelu_exact((A0.y + A1.y + A2.y + A3.y) * inv + bvec.y);
        float o2 = gelu_exact((A0.z + A1.z + A2.z + A3.z) * inv + bvec.z);
        float o3 = gelu_exact((A0.w + A1.w + A2.w + A3.w) * inv + bvec.w);

        ushort4 hv, lv;
        split2(o0, hv.x, lv.x);
        split2(o1, hv.y, lv.y);
        split2(o2, hv.z, lv.z);
        split2(o3, hv.w, lv.w);
        *(ushort4*)&Oh[dst * DD + dim] = hv;
        *(ushort4*)&Ol[dst * DD + dim] = lv;
        if (outf32) {
            float4 o = make_float4(o0, o1, o2, o3);
            *(float4*)&outf32[dst * DD + dim] = o;
        }
    }
}

extern "C" void kernel_launch(void* const* d_in, const int* in_sizes, int n_in,
                              void* d_out, int out_size, void* d_ws, size_t ws_size,
                              hipStream_t stream) {
    const float* x  = (const float*)d_in[0];
    const int* ei   = (const int*)d_in[1];
    const float* W1 = (const float*)d_in[4];
    const float* as1 = (const float*)d_in[5];
    const float* ad1 = (const float*)d_in[6];
    const float* b1 = (const float*)d_in[7];
    const float* W2 = (const float*)d_in[8];
    const float* as2 = (const float*)d_in[9];
    const float* ad2 = (const float*)d_in[10];
    const float* b2 = (const float*)d_in[11];
    const float* W3 = (const float*)d_in[12];
    const float* as3 = (const float*)d_in[13];
    const float* ad3 = (const float*)d_in[14];
    const float* b3 = (const float*)d_in[15];

    float* H = (float*)d_ws;                                      // [N,256] f32
    unsigned short* Xh = (unsigned short*)(H + (size_t)NN * DD);  // [N,256] bf16
    unsigned short* Xl = Xh + (size_t)NN * DD;
    unsigned short* Whl = Xl + (size_t)NN * DD;                   // 6 x [256,256]
    float* sd = (float*)(Whl + (size_t)6 * DD * DD);              // 6*NN: s1,d1,s2,d2,s3,d3
    int* offs = (int*)(sd + (size_t)6 * NN);                      // [N+1]
    int* cursor = offs + (NN + 1);                                // [N]
    int* csr = cursor + NN;                                       // [ETOT]
    int* deg = csr + ETOT;                                        // [N]
    int* csrD = deg + NN;                                         // [ETOT]
    float* wArr = (float*)(csrD + ETOT);                          // [ETOT]
    int* part = (int*)(wArr + ETOT);                              // [NCHUNK]

    float* sA1 = sd,           *dA1 = sd + NN;
    float* sA2 = sd + 2 * NN,  *dA2 = sd + 3 * NN;
    float* sA3 = sd + 4 * NN,  *dA3 = sd + 5 * NN;
    unsigned short* Wt1 = Whl;
    unsigned short* Wt2 = Whl + (size_t)2 * DD * DD;
    unsigned short* Wt3 = Whl + (size_t)4 * DD * DD;

    // 1: normalize+split X, zero s/d, init deg
    norm_k<<<NN / 4, 256, 0, stream>>>(x, Xh, Xl, sd, deg);
    // 2: CSR build — count, 3-pass parallel scan, fill
    count_k<<<(EE + 255) / 256, 256, 0, stream>>>(ei, deg);
    scanA_k<<<NCHUNK, 256, 0, stream>>>(deg, part);
    scanB_k<<<1, 128, 0, stream>>>(part, offs);
    scanC_k<<<NCHUNK, 256, 0, stream>>>(deg, part, offs, cursor, csr, csrD);
    fill_k<<<(EE + 255) / 256, 256, 0, stream>>>(ei, cursor, csr, csrD);
    // 3: all W transposes+splits
    splitw_k<<<dim3(4, 4, 3), 256, 0, stream>>>(W1, W2, W3, Whl);

    dim3 ggrid(GX, DD / 128);
    dim3 sgrid(DD / 32, 313);
    int agrid = (ETOT + 255) / 256;

    // layer 1
    gemm_sd<<<ggrid, 256, 0, stream>>>(Xh, Xl, Wt1, Wt1 + DD * DD, as1, ad1, H, sA1, dA1);
    alpha_k<<<agrid, 256, 0, stream>>>(sA1, dA1, csr, csrD, wArr);
    spmm_k<<<sgrid, 256, 0, stream>>>(H, offs, csr, wArr, b1, Xh, Xl, nullptr);
    // layer 2
    gemm_sd<<<ggrid, 256, 0, stream>>>(Xh, Xl, Wt2, Wt2 + DD * DD, as2, ad2, H, sA2, dA2);
    alpha_k<<<agrid, 256, 0, stream>>>(sA2, dA2, csr, csrD, wArr);
    spmm_k<<<sgrid, 256, 0, stream>>>(H, offs, csr, wArr, b2, Xh, Xl, nullptr);
    // layer 3
    gemm_sd<<<ggrid, 256, 0, stream>>>(Xh, Xl, Wt3, Wt3 + DD * DD, as3, ad3, H, sA3, dA3);
    alpha_k<<<agrid, 256, 0, stream>>>(sA3, dA3, csr, csrD, wArr);
    spmm_k<<<sgrid, 256, 0, stream>>>(H, offs, csr, wArr, b3, Xh, Xl, (float*)d_out);
}

// Round 6
// 306.091 us; speedup vs baseline: 1.4191x; 1.4191x over previous
//
#include <hip/hip_runtime.h>
#include <math.h>

#define NN 20000
#define EE 320000
#define DD 256
#define ETOT (EE + NN)
#define EDGE_CAP 1544   // max edges per 32-dst group (mean 544) + 4 align slack + 4 overshoot
#define NCHUNK ((NN + 255) / 256)  // 79 scan chunks

typedef __attribute__((ext_vector_type(8))) short bf8;
typedef __attribute__((ext_vector_type(4))) float f32x4;

__device__ __forceinline__ float gelu_exact(float x) {
    return 0.5f * x * (1.0f + erff(x * 0.70710678118654752f));
}

// round-to-nearest-even f32 -> bf16 bits
__device__ __forceinline__ unsigned short f2bf(float v) {
    unsigned u = __float_as_uint(v);
    u += 0x7fffu + ((u >> 16) & 1u);
    return (unsigned short)(u >> 16);
}
__device__ __forceinline__ float bf2f(unsigned short h) {
    return __uint_as_float(((unsigned)h) << 16);
}
__device__ __forceinline__ void split2(float v, unsigned short& hi, unsigned short& lo) {
    hi = f2bf(v);
    lo = f2bf(v - bf2f(hi));
}

// ---------------- row-normalize + split X; zero s/d buffers; init deg ----------------
__global__ __launch_bounds__(256) void norm_k(const float* __restrict__ X,
                                              unsigned short* __restrict__ Xh,
                                              unsigned short* __restrict__ Xl,
                                              float* __restrict__ sdZero,  // 6*NN floats
                                              int* __restrict__ deg) {
    int t = threadIdx.x;
    int bid = blockIdx.x;  // 0..4999
    // side duties: zero 24 floats of s/d buffers, init 4 deg entries to 1 (self loop)
    if (t < 24) sdZero[bid * 24 + t] = 0.0f;
    if (t >= 32 && t < 36) deg[bid * 4 + (t - 32)] = 1;

    int wave = (bid * 256 + t) >> 6;
    int lane = t & 63;
    const float4 v = *(const float4*)&X[wave * DD + lane * 4];
    float ss = v.x * v.x + v.y * v.y + v.z * v.z + v.w * v.w;
    for (int off = 32; off > 0; off >>= 1) ss += __shfl_down(ss, off, 64);
    ss = __shfl(ss, 0, 64);
    float n = sqrtf(ss);
    if (n == 0.0f) n = 1e-8f;
    float inv = 1.0f / n;
    float o[4] = {v.x * inv, v.y * inv, v.z * inv, v.w * inv};
    ushort4 hv, lv;
    split2(o[0], hv.x, lv.x);
    split2(o[1], hv.y, lv.y);
    split2(o[2], hv.z, lv.z);
    split2(o[3], hv.w, lv.w);
    *(ushort4*)&Xh[wave * DD + lane * 4] = hv;
    *(ushort4*)&Xl[wave * DD + lane * 4] = lv;
}

// ---------------- W transpose + hi/lo split for all 3 layers (z = layer) ----------------
__global__ __launch_bounds__(256) void splitw_k(const float* __restrict__ W1, const float* __restrict__ W2,
                                                const float* __restrict__ W3, unsigned short* __restrict__ Whl) {
    __shared__ float tile[64][65];
    int t = threadIdx.x;
    int k0 = blockIdx.x * 64;
    int c0 = blockIdx.y * 64;
    int z = blockIdx.z;
    const float* W = (z == 0) ? W1 : (z == 1) ? W2 : W3;
    unsigned short* Wht = Whl + (size_t)z * 2 * DD * DD;
    unsigned short* Wlt = Wht + DD * DD;
#pragma unroll
    for (int i = 0; i < 16; ++i) {
        int idx = t + i * 256;
        int r = idx >> 6, c = idx & 63;
        tile[r][c] = W[(k0 + r) * DD + c0 + c];
    }
    __syncthreads();
#pragma unroll
    for (int i = 0; i < 16; ++i) {
        int idx = t + i * 256;
        int r = idx >> 6, c = idx & 63;
        float v = tile[c][r];
        unsigned short hi, lo;
        split2(v, hi, lo);
        Wht[(c0 + r) * DD + k0 + c] = hi;
        Wlt[(c0 + r) * DD + k0 + c] = lo;
    }
}

// ---------------- CSR build ----------------
__global__ void count_k(const int* __restrict__ ei, int* deg) {
    int e = blockIdx.x * 256 + threadIdx.x;
    if (e < EE) atomicAdd(&deg[ei[EE + e]], 1);
}

// 3-pass parallel scan of deg[NN].
__global__ __launch_bounds__(256) void scanA_k(const int* __restrict__ deg, int* __restrict__ part) {
    __shared__ int red[256];
    int t = threadIdx.x;
    int idx = blockIdx.x * 256 + t;
    red[t] = (idx < NN) ? deg[idx] : 0;
    __syncthreads();
    for (int s = 128; s > 0; s >>= 1) {
        if (t < s) red[t] += red[t + s];
        __syncthreads();
    }
    if (t == 0) part[blockIdx.x] = red[0];
}

__global__ __launch_bounds__(128) void scanB_k(int* __restrict__ part, int* __restrict__ offs) {
    __shared__ int sh[NCHUNK];
    int t = threadIdx.x;
    if (t < NCHUNK) sh[t] = part[t];
    __syncthreads();
    if (t == 0) {
        int run = 0;
        for (int i = 0; i < NCHUNK; ++i) {
            int v = sh[i];
            sh[i] = run;
            run += v;
        }
        offs[NN] = run;  // == ETOT
    }
    __syncthreads();
    if (t < NCHUNK) part[t] = sh[t];
}

__global__ __launch_bounds__(256) void scanC_k(const int* __restrict__ deg, const int* __restrict__ part,
                                               int* __restrict__ offs, int* __restrict__ cursor,
                                               int* __restrict__ csr, int* __restrict__ csrD) {
    __shared__ int sh[256];
    int t = threadIdx.x;
    int idx = blockIdx.x * 256 + t;
    int v = (idx < NN) ? deg[idx] : 0;
    sh[t] = v;
    __syncthreads();
    for (int s = 1; s < 256; s <<= 1) {
        int u = (t >= s) ? sh[t - s] : 0;
        __syncthreads();
        sh[t] += u;
        __syncthreads();
    }
    if (idx < NN) {
        int run = part[blockIdx.x] + sh[t] - v;  // exclusive prefix
        offs[idx] = run;
        cursor[idx] = run + 1;  // slot 0 of segment = self loop
        csr[run] = idx;
        csrD[run] = idx;
    }
}

__global__ void fill_k(const int* __restrict__ ei, int* cursor, int* __restrict__ csr,
                       int* __restrict__ csrD) {
    int e = blockIdx.x * 256 + threadIdx.x;
    if (e < EE) {
        int s = ei[e];
        int d = ei[EE + e];
        int p = atomicAdd(&cursor[d], 1);
        csr[p] = s;
        csrD[p] = d;
    }
}

// ---------------- edge-parallel attention weights ----------------
__global__ __launch_bounds__(256) void alpha_k(const float* __restrict__ sArr,
                                               const float* __restrict__ dArr,
                                               const int* __restrict__ csr,
                                               const int* __restrict__ csrD,
                                               float* __restrict__ wArr) {
    int p = blockIdx.x * 256 + threadIdx.x;
    if (p < ETOT) {
        float a = sArr[csr[p]] + dArr[csrD[p]];
        a = (a > 0.0f) ? a : 0.2f * a;
        wArr[p] = expf(a);
    }
}

// ---------------- MFMA GEMM + fused s,d epilogue ----------------
// 64x128 tile, 4 waves — exact R2 structure (307us config; R3 32x128 and R4
// LDS-transpose-epilogue both regressed: per-block critical path is the cost model
// at 2.4 blocks/CU, so keep stores scattered/asynchronous and tiles big).
// Only change vs R2: LDB 40->36. 18-dword row stride -> 16 distinct bank starts
// (18r mod 32 distinct for r=0..15) -> <=2-way aliasing (free) on both ds_write
// and ds_read_b128. Verified in R4: conflicts 1.92M -> 160K.
#define LDB 36
#define GX ((NN + 63) / 64)  // 313 gemm tile rows
__global__ __launch_bounds__(256) void gemm_sd(const unsigned short* __restrict__ Xh,
                                               const unsigned short* __restrict__ Xl,
                                               const unsigned short* __restrict__ Bh,
                                               const unsigned short* __restrict__ Bl,
                                               const float* __restrict__ a_s,
                                               const float* __restrict__ a_d,
                                               float* __restrict__ H,
                                               float* __restrict__ sArr,
                                               float* __restrict__ dArr) {
    __shared__ unsigned short sBh[128 * LDB], sBl[128 * LDB];
    int t = threadIdx.x;
    int m0 = blockIdx.x * 64;
    int n0 = blockIdx.y * 128;
    int w = t >> 6, l = t & 63;
    int rofs = l & 15, kch = l >> 4;

    f32x4 acc[8] = {};

    int c1 = t, c2 = t + 256;
    int br1 = c1 >> 2, bo1 = (c1 & 3) * 8;
    int br2 = c2 >> 2, bo2 = (c2 & 3) * 8;
    const unsigned short* Bh1 = &Bh[(n0 + br1) * DD + bo1];
    const unsigned short* Bh2 = &Bh[(n0 + br2) * DD + bo2];
    const unsigned short* Bl1 = &Bl[(n0 + br1) * DD + bo1];
    const unsigned short* Bl2 = &Bl[(n0 + br2) * DD + bo2];
    bf8 rbh1 = *(const bf8*)Bh1;
    bf8 rbh2 = *(const bf8*)Bh2;
    bf8 rbl1 = *(const bf8*)Bl1;
    bf8 rbl2 = *(const bf8*)Bl2;

    int arow = m0 + w * 16 + rofs;
    bool aval = arow < NN;
    const unsigned short* Ahp = &Xh[(size_t)arow * DD + kch * 8];
    const unsigned short* Alp = &Xl[(size_t)arow * DD + kch * 8];
    bf8 zero = {0, 0, 0, 0, 0, 0, 0, 0};
    bf8 ah = aval ? *(const bf8*)Ahp : zero;
    bf8 al = aval ? *(const bf8*)Alp : zero;

    for (int k0 = 0; k0 < DD; k0 += 32) {
        if (k0) __syncthreads();
        *(bf8*)&sBh[br1 * LDB + bo1] = rbh1;
        *(bf8*)&sBh[br2 * LDB + bo2] = rbh2;
        *(bf8*)&sBl[br1 * LDB + bo1] = rbl1;
        *(bf8*)&sBl[br2 * LDB + bo2] = rbl2;
        __syncthreads();
        int kn = k0 + 32;
        bf8 nah = zero, nal = zero;
        if (kn < DD) {
            rbh1 = *(const bf8*)(Bh1 + kn);
            rbh2 = *(const bf8*)(Bh2 + kn);
            rbl1 = *(const bf8*)(Bl1 + kn);
            rbl2 = *(const bf8*)(Bl2 + kn);
            if (aval) {
                nah = *(const bf8*)(Ahp + kn);
                nal = *(const bf8*)(Alp + kn);
            }
        }
#pragma unroll
        for (int nt = 0; nt < 8; ++nt) {
            int r = nt * 16 + rofs;
            bf8 bh = *(const bf8*)&sBh[r * LDB + kch * 8];
            bf8 bl = *(const bf8*)&sBl[r * LDB + kch * 8];
            acc[nt] = __builtin_amdgcn_mfma_f32_16x16x32_bf16(ah, bh, acc[nt], 0, 0, 0);
            acc[nt] = __builtin_amdgcn_mfma_f32_16x16x32_bf16(ah, bl, acc[nt], 0, 0, 0);
            acc[nt] = __builtin_amdgcn_mfma_f32_16x16x32_bf16(al, bh, acc[nt], 0, 0, 0);
        }
        ah = nah;
        al = nal;
    }
    // C/D layout: col = lane&15, row = (lane>>4)*4 + reg  [m89]
    int row0 = m0 + w * 16 + (l >> 4) * 4;
    int colb = l & 15;
    float sp[4] = {0, 0, 0, 0}, dp[4] = {0, 0, 0, 0};
#pragma unroll
    for (int nt = 0; nt < 8; ++nt) {
        int cc = n0 + nt * 16 + colb;
        float vas = a_s[cc], vad = a_d[cc];
#pragma unroll
        for (int r = 0; r < 4; ++r) {
            int row = row0 + r;
            if (row < NN) H[(size_t)row * DD + cc] = acc[nt][r];
            sp[r] += acc[nt][r] * vas;
            dp[r] += acc[nt][r] * vad;
        }
    }
#pragma unroll
    for (int m = 1; m < 16; m <<= 1) {
#pragma unroll
        for (int r = 0; r < 4; ++r) {
            sp[r] += __shfl_xor(sp[r], m, 64);
            dp[r] += __shfl_xor(dp[r], m, 64);
        }
    }
    if (colb == 0) {
#pragma unroll
        for (int r = 0; r < 4; ++r) {
            int row = row0 + r;
            if (row < NN) {
                atomicAdd(&sArr[row], sp[r]);
                atomicAdd(&dArr[row], dp[r]);
            }
        }
    }
}

// ---------------- fused strip SpMM + bias + gelu + split ----------------
__global__ __launch_bounds__(256) void spmm_k(const float* __restrict__ H,
                                              const int* __restrict__ offs,
                                              const int* __restrict__ csr,
                                              const float* __restrict__ wArr,
                                              const float* __restrict__ bias,
                                              unsigned short* __restrict__ Oh,
                                              unsigned short* __restrict__ Ol,
                                              float* __restrict__ outf32) {
    __shared__ float wLds[EDGE_CAP];
    __shared__ int sLds[EDGE_CAP];
    int t = threadIdx.x;
    int sub = t & 7;
    int g = t >> 3;
    int dim = blockIdx.x * 32 + sub * 4;
    const float* Hs = H + dim;
    const float4 bvec = *(const float4*)&bias[dim];

    for (int grp = blockIdx.y; grp < NN / 32; grp += (int)gridDim.y) {
        if (grp != (int)blockIdx.y) __syncthreads();  // LDS reuse fence
        int dst0 = grp * 32;
        int dst = dst0 + g;
        int blkBeg = offs[dst0];
        int blkEnd = offs[dst0 + 32];
        int base = blkBeg & ~3;
        int cnt = blkEnd - base;
        // coalesced copy of this group's weight/src window into LDS
        for (int i = t * 4; i < cnt; i += 1024) {
            *(float4*)&wLds[i] = *(const float4*)&wArr[base + i];
            *(int4*)&sLds[i] = *(const int4*)&csr[base + i];
        }
        int beg = offs[dst], end = offs[dst + 1];
        __syncthreads();

        // den reduce (LDS only)
        float den = 0.0f;
        for (int e = beg + sub; e < end; e += 8) den += wLds[e - base];
        den += __shfl_xor(den, 1, 64);
        den += __shfl_xor(den, 2, 64);
        den += __shfl_xor(den, 4, 64);
        float inv = 1.0f / den;

        // gather pass: unnormalized accumulate
        float4 A0 = make_float4(0, 0, 0, 0), A1 = A0, A2 = A0, A3 = A0;
        int e = beg - base, lend = end - base;
        for (; e + 3 < lend; e += 4) {
            int s0 = sLds[e], s1 = sLds[e + 1], s2 = sLds[e + 2], s3 = sLds[e + 3];
            float w0 = wLds[e], w1 = wLds[e + 1], w2 = wLds[e + 2], w3 = wLds[e + 3];
            const float4 h0 = *(const float4*)&Hs[(size_t)s0 * DD];
            const float4 h1 = *(const float4*)&Hs[(size_t)s1 * DD];
            const float4 h2 = *(const float4*)&Hs[(size_t)s2 * DD];
            const float4 h3 = *(const float4*)&Hs[(size_t)s3 * DD];
            A0.x += w0 * h0.x; A0.y += w0 * h0.y; A0.z += w0 * h0.z; A0.w += w0 * h0.w;
            A1.x += w1 * h1.x; A1.y += w1 * h1.y; A1.z += w1 * h1.z; A1.w += w1 * h1.w;
            A2.x += w2 * h2.x; A2.y += w2 * h2.y; A2.z += w2 * h2.z; A2.w += w2 * h2.w;
            A3.x += w3 * h3.x; A3.y += w3 * h3.y; A3.z += w3 * h3.z; A3.w += w3 * h3.w;
        }
        for (; e < lend; ++e) {
            int s0 = sLds[e];
            float w0 = wLds[e];
            const float4 h0 = *(const float4*)&Hs[(size_t)s0 * DD];
            A0.x += w0 * h0.x; A0.y += w0 * h0.y; A0.z += w0 * h0.z; A0.w += w0 * h0.w;
        }

        float o0 = gelu_exact((A0.x + A1.x + A2.x + A3.x) * inv + bvec.x);
        float o1 = gelu_exact((A0.y + A1.y + A2.y + A3.y) * inv + bvec.y);
        float o2 = gelu_exact((A0.z + A1.z + A2.z + A3.z) * inv + bvec.z);
        float o3 = gelu_exact((A0.w + A1.w + A2.w + A3.w) * inv + bvec.w);

        ushort4 hv, lv;
        split2(o0, hv.x, lv.x);
        split2(o1, hv.y, lv.y);
        split2(o2, hv.z, lv.z);
        split2(o3, hv.w, lv.w);
        *(ushort4*)&Oh[dst * DD + dim] = hv;
        *(ushort4*)&Ol[dst * DD + dim] = lv;
        if (outf32) {
            float4 o = make_float4(o0, o1, o2, o3);
            *(float4*)&outf32[dst * DD + dim] = o;
        }
    }
}

extern "C" void kernel_launch(void* const* d_in, const int* in_sizes, int n_in,
                              void* d_out, int out_size, void* d_ws, size_t ws_size,
                              hipStream_t stream) {
    const float* x  = (const float*)d_in[0];
    const int* ei   = (const int*)d_in[1];
    const float* W1 = (const float*)d_in[4];
    const float* as1 = (const float*)d_in[5];
    const float* ad1 = (const float*)d_in[6];
    const float* b1 = (const float*)d_in[7];
    const float* W2 = (const float*)d_in[8];
    const float* as2 = (const float*)d_in[9];
    const float* ad2 = (const float*)d_in[10];
    const float* b2 = (const float*)d_in[11];
    const float* W3 = (const float*)d_in[12];
    const float* as3 = (const float*)d_in[13];
    const float* ad3 = (const float*)d_in[14];
    const float* b3 = (const float*)d_in[15];

    float* H = (float*)d_ws;                                      // [N,256] f32
    unsigned short* Xh = (unsigned short*)(H + (size_t)NN * DD);  // [N,256] bf16
    unsigned short* Xl = Xh + (size_t)NN * DD;
    unsigned short* Whl = Xl + (size_t)NN * DD;                   // 6 x [256,256]
    float* sd = (float*)(Whl + (size_t)6 * DD * DD);              // 6*NN: s1,d1,s2,d2,s3,d3
    int* offs = (int*)(sd + (size_t)6 * NN);                      // [N+1]
    int* cursor = offs + (NN + 1);                                // [N]
    int* csr = cursor + NN;                                       // [ETOT]
    int* deg = csr + ETOT;                                        // [N]
    int* csrD = deg + NN;                                         // [ETOT]
    float* wArr = (float*)(csrD + ETOT);                          // [ETOT]
    int* part = (int*)(wArr + ETOT);                              // [NCHUNK]

    float* sA1 = sd,           *dA1 = sd + NN;
    float* sA2 = sd + 2 * NN,  *dA2 = sd + 3 * NN;
    float* sA3 = sd + 4 * NN,  *dA3 = sd + 5 * NN;
    unsigned short* Wt1 = Whl;
    unsigned short* Wt2 = Whl + (size_t)2 * DD * DD;
    unsigned short* Wt3 = Whl + (size_t)4 * DD * DD;

    // 1: normalize+split X, zero s/d, init deg
    norm_k<<<NN / 4, 256, 0, stream>>>(x, Xh, Xl, sd, deg);
    // 2: CSR build — count, 3-pass parallel scan, fill
    count_k<<<(EE + 255) / 256, 256, 0, stream>>>(ei, deg);
    scanA_k<<<NCHUNK, 256, 0, stream>>>(deg, part);
    scanB_k<<<1, 128, 0, stream>>>(part, offs);
    scanC_k<<<NCHUNK, 256, 0, stream>>>(deg, part, offs, cursor, csr, csrD);
    fill_k<<<(EE + 255) / 256, 256, 0, stream>>>(ei, cursor, csr, csrD);
    // 3: all W transposes+splits
    splitw_k<<<dim3(4, 4, 3), 256, 0, stream>>>(W1, W2, W3, Whl);

    dim3 ggrid(GX, DD / 128);
    dim3 sgrid(DD / 32, 313);
    int agrid = (ETOT + 255) / 256;

    // layer 1
    gemm_sd<<<ggrid, 256, 0, stream>>>(Xh, Xl, Wt1, Wt1 + DD * DD, as1, ad1, H, sA1, dA1);
    alpha_k<<<agrid, 256, 0, stream>>>(sA1, dA1, csr, csrD, wArr);
    spmm_k<<<sgrid, 256, 0, stream>>>(H, offs, csr, wArr, b1, Xh, Xl, nullptr);
    // layer 2
    gemm_sd<<<ggrid, 256, 0, stream>>>(Xh, Xl, Wt2, Wt2 + DD * DD, as2, ad2, H, sA2, dA2);
    alpha_k<<<agrid, 256, 0, stream>>>(sA2, dA2, csr, csrD, wArr);
    spmm_k<<<sgrid, 256, 0, stream>>>(H, offs, csr, wArr, b2, Xh, Xl, nullptr);
    // layer 3
    gemm_sd<<<ggrid, 256, 0, stream>>>(Xh, Xl, Wt3, Wt3 + DD * DD, as3, ad3, H, sA3, dA3);
    alpha_k<<<agrid, 256, 0, stream>>>(sA3, dA3, csr, csrD, wArr);
    spmm_k<<<sgrid, 256, 0, stream>>>(H, offs, csr, wArr, b3, Xh, Xl, (float*)d_out);
}